// Round 12
// baseline (778.170 us; speedup 1.0000x reference)
//
#include <hip/hip_runtime.h>
#include <math.h>

#define NTOK 4096
#define DD   1024
#define VV   50257

#define LOG2E 1.4426950408889634f
#define LN2F  0.6931471805599453f
#define L2E32 (1.4426950408889634f / 32.0f)

// ---- fast path: 128x128 tile, MX-fp4, 32B-row transposed planes,
// ---- direct global->VGPR i32x8 tuples (no LDS, no movs, no barriers)
#define BM2   128
#define BN2   128
#define NPH   16              // phases of K=64 elems
#define NC2   393             // ceil(50257/128)
#define VPAD2 (NC2*BM2)       // 50304 padded vocab rows
#define NMT2  (NTOK/BM2)      // 32 token tiles
#define NBLK2 (NMT2*NC2)      // 12576 = 8 * 1572
#define CPX2  (NBLK2/8)       // 1572
#define RB    512             // fp4 bytes per row total (1024 elems / 2)
#define PSA32 ((size_t)NTOK*32)    // bytes per plane, transposed X
#define PSB32 ((size_t)VPAD2*32)   // bytes per plane, transposed E

// ---- fallback (round-1 fp32) path geometry ----
#define TT 16
#define VT 128
#define KT 32
#define NSUB_O 8
#define CHUNK_O (VT*NSUB_O)
#define NCHUNK_O ((VV + CHUNK_O - 1)/CHUNK_O)
#define NTTILE_O (NTOK/TT)

typedef __attribute__((ext_vector_type(4)))  int   i32x4;
typedef __attribute__((ext_vector_type(8)))  int   i32x8;
typedef __attribute__((ext_vector_type(16))) float f32x16;
typedef i32x8 __attribute__((aligned(16)))   i32x8u;   // 16B-aligned 32B load

// fp32 -> e2m1 code (sign + 3-bit). Grid: {0,0.5,1,1.5,2,3,4,6}, RTNE-ish.
__device__ __forceinline__ unsigned e2m1(float v) {
    unsigned s = (__float_as_uint(v) >> 28) & 0x8u;
    float a = fabsf(v);
    unsigned c;
    if      (a <  0.25f) c = 0u;
    else if (a <= 0.75f) c = 1u;
    else if (a <= 1.25f) c = 2u;
    else if (a <  1.75f) c = 3u;
    else if (a <= 2.50f) c = 4u;
    else if (a <  3.50f) c = 5u;
    else if (a <= 5.00f) c = 6u;
    else                 c = 7u;
    return s | c;
}

// pack 8 consecutive elems (two float4) -> 4 bytes (elem 2j low nibble of byte j)
__device__ __forceinline__ unsigned pack8_e2m1(float4 a, float4 b) {
    unsigned b0 = e2m1(a.x) | (e2m1(a.y) << 4);
    unsigned b1 = e2m1(a.z) | (e2m1(a.w) << 4);
    unsigned b2 = e2m1(b.x) | (e2m1(b.y) << 4);
    unsigned b3 = e2m1(b.z) | (e2m1(b.w) << 4);
    return b0 | (b1 << 8) | (b2 << 16) | (b3 << 24);
}

// ---------------------------------------------------------------------------
// fp32 -> fp4 TRANSPOSED X, 32B rows: plane P (0..15) of [NTOK][32B]; plane P
// row r holds elems [P*64, P*64+64) of token r. Block = 16 rows x 16 planes.
// Fragment element sets are byte-identical to the validated R9-11 mapping.
// ---------------------------------------------------------------------------
__global__ __launch_bounds__(256) void convX4T(const float* __restrict__ X,
                                               unsigned char* __restrict__ Xq) {
    int r16 = threadIdx.x & 15;
    int P   = threadIdx.x >> 4;           // plane 0..15
    int row = blockIdx.x * 16 + r16;
    const float4* src = (const float4*)(X + (size_t)row * DD + P * 64);
    unsigned w[8];
    #pragma unroll
    for (int j = 0; j < 8; ++j) w[j] = pack8_e2m1(src[2 * j], src[2 * j + 1]);
    unsigned char* dst = Xq + ((size_t)P * NTOK + row) * 32;
    *(uint4*)dst        = make_uint4(w[0], w[1], w[2], w[3]);
    *(uint4*)(dst + 16) = make_uint4(w[4], w[5], w[6], w[7]);
}

// fp32 -> fp4 TRANSPOSED (32*E), zero-padded to VPAD2 rows.
__global__ __launch_bounds__(256) void convE4T(const float* __restrict__ E,
                                               unsigned char* __restrict__ Eq) {
    int r16 = threadIdx.x & 15;
    int P   = threadIdx.x >> 4;
    int row = blockIdx.x * 16 + r16;
    float4 f[16];
    #pragma unroll
    for (int j = 0; j < 16; ++j) f[j] = make_float4(0.f, 0.f, 0.f, 0.f);
    if (row < VV) {
        const float4* src = (const float4*)(E + (size_t)row * DD + P * 64);
        #pragma unroll
        for (int j = 0; j < 16; ++j) {
            float4 v = src[j];
            v.x *= 32.f; v.y *= 32.f; v.z *= 32.f; v.w *= 32.f;
            f[j] = v;
        }
    }
    unsigned w[8];
    #pragma unroll
    for (int j = 0; j < 8; ++j) w[j] = pack8_e2m1(f[2 * j], f[2 * j + 1]);
    unsigned char* dst = Eq + ((size_t)P * VPAD2 + row) * 32;
    *(uint4*)dst        = make_uint4(w[0], w[1], w[2], w[3]);
    *(uint4*)(dst + 16) = make_uint4(w[4], w[5], w[6], w[7]);
}

// ---------------------------------------------------------------------------
// Label logits in fp32 (exact). One block per token.
// ---------------------------------------------------------------------------
__global__ __launch_bounds__(256) void ce_label(
    const float* __restrict__ X, const float* __restrict__ E,
    const float* __restrict__ bias, const int* __restrict__ labels,
    float* __restrict__ lab_out)
{
    int t = blockIdx.x;
    int lbl = labels[t];
    const float4* x = (const float4*)(X + (size_t)t * DD);
    const float4* e = (const float4*)(E + (size_t)lbl * DD);
    int i = threadIdx.x;
    float4 a = x[i], b4 = e[i];
    float s = a.x*b4.x + a.y*b4.y + a.z*b4.z + a.w*b4.w;
    #pragma unroll
    for (int off = 32; off; off >>= 1) s += __shfl_down(s, off, 64);
    __shared__ float red[4];
    if ((threadIdx.x & 63) == 0) red[threadIdx.x >> 6] = s;
    __syncthreads();
    if (threadIdx.x == 0)
        lab_out[t] = red[0] + red[1] + red[2] + red[3] + bias[lbl];
}

// ---------------------------------------------------------------------------
// Fused MX-fp4 MFMA GEMM, 128x128 tile, ZERO-ASSEMBLY register operands.
// 256 threads = 4 waves (2M x 2N); wave tile 64x64; per phase (K=64, plane P)
// 4 MFMAs (mi2 x ni2), acc[2][2] f32x16. Each operand tuple is ONE C-level
// 32-B load (*(const i32x8u*)addr -> two dwordx4 forming one SSA value ->
// regalloc puts them straight into the aligned 8-reg tuple, no v_movs):
// low quad = the 16-B fragment (HW reads ONLY the low 4 regs for fp4 --
// proven by 3 rounds of absmax=0 with zeroed upper quads); upper quad =
// adjacent real bytes, ignored. F/G phase double-buffer, distance 2 phases.
// ---------------------------------------------------------------------------
struct Ph { i32x8 A[2]; i32x8 B[2]; };

__global__ __launch_bounds__(256, 3) void ce_p4(
    const unsigned char* __restrict__ Xq, const unsigned char* __restrict__ Eq,
    const float* __restrict__ bias, float* __restrict__ pairs)
{
    __shared__ float sums[256];      // epilogue only (1 KB)

    const int tid  = threadIdx.x;
    const int lane = tid & 63;
    const int w    = tid >> 6;       // 0..3
    const int wr   = w >> 1;         // 0..1  M half (64 rows)
    const int wc   = w & 1;          // 0..1  N half (64 cols)
    const int h    = lane >> 5;      // k-half selector (16 B within 32-B row)
    const int r32  = lane & 31;      // row (A) / col (B) within 32

    // bijective XCD chunking; nc-major within each XCD (E-panel L2 locality)
    const int l       = blockIdx.x;
    const int logical = (l & 7) * CPX2 + (l >> 3);
    const int nc   = logical >> 5;   // / NMT2(32)
    const int mt   = logical & 31;
    const int tok0 = mt * BM2;
    const int v0   = nc * BN2;

    // per-lane tuple bases; phase p adds p*PS*32, mi/ni adds 32 rows = 1024 B
    const unsigned char* aB = Xq + ((size_t)(tok0 + wr * 64 + r32)) * 32 + h * 16;
    const unsigned char* bB = Eq + ((size_t)(v0 + wc * 64 + r32)) * 32 + h * 16;

#define LOADPH(S, p) do {                                                     \
        const unsigned char* _a = aB + (size_t)(p) * PSA32;                   \
        const unsigned char* _b = bB + (size_t)(p) * PSB32;                   \
        S.A[0] = *(const i32x8u*)(_a);                                        \
        S.A[1] = *(const i32x8u*)(_a + 1024);                                 \
        S.B[0] = *(const i32x8u*)(_b);                                        \
        S.B[1] = *(const i32x8u*)(_b + 1024);                                 \
    } while (0)

#define MFMAPH(S) do {                                                        \
        __builtin_amdgcn_s_setprio(1);                                        \
        _Pragma("unroll")                                                     \
        for (int mi = 0; mi < 2; ++mi)                                        \
            _Pragma("unroll")                                                 \
            for (int ni = 0; ni < 2; ++ni)                                    \
                acc[mi][ni] = __builtin_amdgcn_mfma_scale_f32_32x32x64_f8f6f4( \
                    S.A[mi], S.B[ni], acc[mi][ni],                            \
                    4, 4,                     /* cbsz = blgp = fp4 */         \
                    0, 0x7f7f7f7f,            /* scale A = 2^0 */             \
                    0, 0x7f7f7f7f);           /* scale B = 2^0 */             \
        __builtin_amdgcn_s_setprio(0);                                        \
    } while (0)

    f32x16 acc[2][2];
    #pragma unroll
    for (int mi = 0; mi < 2; ++mi)
        #pragma unroll
        for (int ni = 0; ni < 2; ++ni)
            #pragma unroll
            for (int g = 0; g < 16; ++g)
                acc[mi][ni][g] = 0.f;

    Ph F, G;
    LOADPH(F, 0);
    LOADPH(G, 1);
    #pragma unroll 1
    for (int p = 0; p < NPH; p += 2) {
        MFMAPH(F);
        if (p + 2 < NPH) LOADPH(F, p + 2);
        MFMAPH(G);
        if (p + 3 < NPH) LOADPH(G, p + 3);
    }
#undef LOADPH
#undef MFMAPH

    // ---- epilogue: fixed-max sum of exp (base-2), masked pad cols ----
    // acc = X . (32 E); 1/32 folded into the exp2 slope (L2E32).
    // 32x32 C/D map: col = lane&31, row = (g&3) + 8*(g>>2) + 4*h
    float bb[2];
    #pragma unroll
    for (int ni = 0; ni < 2; ++ni) {
        int v = v0 + wc * 64 + ni * 32 + r32;
        bb[ni] = (v < VV) ? bias[v] * LOG2E : -INFINITY;
    }

    #pragma unroll
    for (int mi = 0; mi < 2; ++mi) {
        float run[16];
        #pragma unroll
        for (int g = 0; g < 16; ++g)
            run[g] = exp2f(fmaf(acc[mi][0][g], L2E32, bb[0]))
                   + exp2f(fmaf(acc[mi][1][g], L2E32, bb[1]));
        #pragma unroll
        for (int g = 0; g < 16; ++g) {
            float s = run[g];
            s += __shfl_xor(s, 1);  s += __shfl_xor(s, 2);
            s += __shfl_xor(s, 4);  s += __shfl_xor(s, 8);
            s += __shfl_xor(s, 16);
            run[g] = s;
        }
        if (r32 == 0) {
            #pragma unroll
            for (int g = 0; g < 16; ++g) {
                int rl = (g & 3) + 8 * (g >> 2) + 4 * h;
                sums[wc * 128 + wr * 64 + mi * 32 + rl] = run[g];
            }
        }
    }
    __syncthreads();
    if (tid < 128) {
        float S = sums[tid] + sums[128 + tid];
        pairs[(size_t)nc * NTOK + tok0 + tid] = S;
    }
}

// ---------------------------------------------------------------------------
// Combine NC2 partial sums per token -> per-block loss partial sums
// ---------------------------------------------------------------------------
__global__ __launch_bounds__(256) void ce_combine(
    const float* __restrict__ pairs, const float* __restrict__ lab,
    float* __restrict__ partials)
{
    int t = blockIdx.x * 256 + threadIdx.x;    // grid 16 x 256 = 4096 tokens
    float S = 0.f;
    for (int c = 0; c < NC2; ++c) S += pairs[(size_t)c * NTOK + t];
    float acc = log2f(S) * LN2F - lab[t];
    #pragma unroll
    for (int off = 32; off; off >>= 1) acc += __shfl_down(acc, off, 64);
    __shared__ float red[4];
    if ((threadIdx.x & 63) == 0) red[threadIdx.x >> 6] = acc;
    __syncthreads();
    if (threadIdx.x == 0)
        partials[blockIdx.x] = red[0] + red[1] + red[2] + red[3];
}

__global__ void ce_sum(const float* __restrict__ partials, float* __restrict__ out) {
    if (threadIdx.x == 0) {
        float s = 0.f;
        for (int i = 0; i < 16; ++i) s += partials[i];
        out[0] = s / (float)NTOK;
    }
}

// ---------------------------------------------------------------------------
// FALLBACK path (round-1 fp32 kernels) — used only if ws_size is too small
// ---------------------------------------------------------------------------
__global__ __launch_bounds__(256) void ce_partial_old(
    const float* __restrict__ X, const float* __restrict__ E,
    const float* __restrict__ bias, float* __restrict__ pairs)
{
    int ttile = blockIdx.x;
    int chunk = blockIdx.y;
    int tid = threadIdx.x;
    int ty = tid >> 4;
    int tx = tid & 15;

    __shared__ float As_[TT][KT + 1];
    __shared__ float Bs_[VT][KT + 1];

    int tok0 = ttile * TT;
    float run_m = -INFINITY, run_s = 0.f;

    for (int sub = 0; sub < NSUB_O; ++sub) {
        int v0 = chunk * CHUNK_O + sub * VT;
        float acc[8];
        #pragma unroll
        for (int c = 0; c < 8; ++c) acc[c] = 0.f;

        for (int k0 = 0; k0 < DD; k0 += KT) {
            __syncthreads();
            {
                const float2 a2 = *(const float2*)(X + (size_t)(tok0 + ty) * DD + k0 + 2 * tx);
                As_[ty][2 * tx]     = a2.x;
                As_[ty][2 * tx + 1] = a2.y;
            }
            #pragma unroll
            for (int j = 0; j < 4; ++j) {
                int idx = tid + 256 * j;
                int r  = idx >> 3;
                int c4 = (idx & 7) << 2;
                int v = v0 + r;
                float4 b4 = make_float4(0.f, 0.f, 0.f, 0.f);
                if (v < VV)
                    b4 = *(const float4*)(E + (size_t)v * DD + k0 + c4);
                Bs_[r][c4]     = b4.x;
                Bs_[r][c4 + 1] = b4.y;
                Bs_[r][c4 + 2] = b4.z;
                Bs_[r][c4 + 3] = b4.w;
            }
            __syncthreads();
            #pragma unroll
            for (int k = 0; k < KT; ++k) {
                float a = As_[ty][k];
                #pragma unroll
                for (int c = 0; c < 8; ++c)
                    acc[c] += a * Bs_[tx + 16 * c][k];
            }
        }

        float lv[8];
        float lm = -INFINITY;
        #pragma unroll
        for (int c = 0; c < 8; ++c) {
            int v = v0 + tx + 16 * c;
            float lg = (v < VV) ? acc[c] + bias[v] : -INFINITY;
            lv[c] = lg;
            lm = fmaxf(lm, lg);
        }
        if (lm != -INFINITY) {
            float nm = fmaxf(run_m, lm);
            float s = run_s * expf(run_m - nm);
            #pragma unroll
            for (int c = 0; c < 8; ++c) s += expf(lv[c] - nm);
            run_m = nm; run_s = s;
        }
    }

    #pragma unroll
    for (int off = 1; off < 16; off <<= 1) {
        float om = __shfl_xor(run_m, off, 64);
        float os = __shfl_xor(run_s, off, 64);
        if (os > 0.f) {
            if (om > run_m) { run_s = run_s * expf(run_m - om) + os; run_m = om; }
            else            { run_s += os * expf(om - run_m); }
        }
    }
    if (tx == 0) {
        size_t o = ((size_t)chunk * NTOK + tok0 + ty) * 2;
        pairs[o]     = run_m;
        pairs[o + 1] = run_s;
    }
}

__global__ __launch_bounds__(256) void ce_final_old(
    const float* __restrict__ pairs, const float* __restrict__ lab,
    float* __restrict__ out)
{
    int tid = threadIdx.x;
    float acc = 0.f;
    for (int t = tid; t < NTOK; t += 256) {
        float M = -INFINITY, S = 0.f;
        for (int c = 0; c < NCHUNK_O; ++c) {
            size_t o = ((size_t)c * NTOK + t) * 2;
            float m = pairs[o], s = pairs[o + 1];
            if (s > 0.f) {
                if (m > M) { S = S * expf(M - m) + s; M = m; }
                else       { S += s * expf(m - M); }
            }
        }
        acc += (M + logf(S)) - lab[t];
    }
    #pragma unroll
    for (int off = 32; off; off >>= 1) acc += __shfl_down(acc, off, 64);
    __shared__ float red[4];
    if ((tid & 63) == 0) red[tid >> 6] = acc;
    __syncthreads();
    if (tid == 0)
        out[0] = (red[0] + red[1] + red[2] + red[3]) / (float)NTOK;
}

// ---------------------------------------------------------------------------
extern "C" void kernel_launch(void* const* d_in, const int* in_sizes, int n_in,
                              void* d_out, int out_size, void* d_ws, size_t ws_size,
                              hipStream_t stream) {
    const float* X      = (const float*)d_in[0];   // [4096,1024]
    const float* E      = (const float*)d_in[1];   // [50257,1024]
    const float* bias   = (const float*)d_in[2];   // [50257]
    const int*   labels = (const int*)d_in[3];     // [4096]
    float* out = (float*)d_out;

    char* ws = (char*)d_ws;
    const size_t off_lab   = 0;                                  // 16 KB
    const size_t off_pairs = 16384;
    const size_t sz_pairs  = (size_t)NC2 * NTOK * 4;             // ~6.4 MB
    const size_t off_part  = off_pairs + sz_pairs;
    const size_t off_Xq    = off_part + 1024;                    // 16B aligned
    const size_t off_Eq    = off_Xq + (size_t)NTOK * RB;         // 2 MB
    const size_t need      = off_Eq + (size_t)VPAD2 * RB + 64;   // +pad for +16 reads

    float* lab = (float*)(ws + off_lab);

    if (ws_size >= need) {
        unsigned char* Xq = (unsigned char*)(ws + off_Xq);
        unsigned char* Eq = (unsigned char*)(ws + off_Eq);
        float* pairs    = (float*)(ws + off_pairs);
        float* partials = (float*)(ws + off_part);

        convX4T<<<NTOK / 16, 256, 0, stream>>>(X, Xq);
        convE4T<<<VPAD2 / 16, 256, 0, stream>>>(E, Eq);
        ce_label<<<NTOK, 256, 0, stream>>>(X, E, bias, labels, lab);
        ce_p4<<<NBLK2, 256, 0, stream>>>(Xq, Eq, bias, pairs);
        ce_combine<<<16, 256, 0, stream>>>(pairs, lab, partials);
        ce_sum<<<1, 64, 0, stream>>>(partials, out);
    } else {
        float* pairs = (float*)(ws + 16384);
        ce_label<<<NTOK, 256, 0, stream>>>(X, E, bias, labels, lab);
        dim3 grid(NTTILE_O, NCHUNK_O);
        ce_partial_old<<<grid, 256, 0, stream>>>(X, E, bias, pairs);
        ce_final_old<<<1, 256, 0, stream>>>(pairs, lab, out);
    }
}

// Round 13
// 252.626 us; speedup vs baseline: 3.0803x; 3.0803x over previous
//
#include <hip/hip_runtime.h>
#include <math.h>

#define NTOK 4096
#define DD   1024
#define VV   50257

#define LOG2E 1.4426950408889634f
#define LN2F  0.6931471805599453f
#define L2E32 (1.4426950408889634f / 32.0f)

// ---- fast path: 128x128 tile, MX-fp4, 16B-row transposed planes,
// ---- direct global->VGPR i32x4 fragments + inline-asm MFMA (4-reg fp4 form)
#define BM2   128
#define BN2   128
#define NKT2  8               // K-tiles of 128 elems
#define NC2   393             // ceil(50257/128)
#define VPAD2 (NC2*BM2)       // 50304 padded vocab rows
#define NMT2  (NTOK/BM2)      // 32 token tiles
#define NBLK2 (NMT2*NC2)      // 12576 = 8 * 1572
#define CPX2  (NBLK2/8)       // 1572
#define RB    512             // fp4 bytes per row total (1024 elems / 2)
#define PSA   ((size_t)NTOK*16)    // bytes per plane in transposed X
#define PSB   ((size_t)VPAD2*16)   // bytes per plane in transposed E

// ---- fallback (round-1 fp32) path geometry ----
#define TT 16
#define VT 128
#define KT 32
#define NSUB_O 8
#define CHUNK_O (VT*NSUB_O)
#define NCHUNK_O ((VV + CHUNK_O - 1)/CHUNK_O)
#define NTTILE_O (NTOK/TT)

typedef __attribute__((ext_vector_type(4)))  int   i32x4;
typedef __attribute__((ext_vector_type(16))) float f32x16;

// fp32 -> e2m1 code (sign + 3-bit). Grid: {0,0.5,1,1.5,2,3,4,6}, RTNE-ish.
__device__ __forceinline__ unsigned e2m1(float v) {
    unsigned s = (__float_as_uint(v) >> 28) & 0x8u;
    float a = fabsf(v);
    unsigned c;
    if      (a <  0.25f) c = 0u;
    else if (a <= 0.75f) c = 1u;
    else if (a <= 1.25f) c = 2u;
    else if (a <  1.75f) c = 3u;
    else if (a <= 2.50f) c = 4u;
    else if (a <  3.50f) c = 5u;
    else if (a <= 5.00f) c = 6u;
    else                 c = 7u;
    return s | c;
}

// pack 8 consecutive elems (two float4) -> 4 bytes (elem 2j low nibble of byte j)
__device__ __forceinline__ unsigned pack8_e2m1(float4 a, float4 b) {
    unsigned b0 = e2m1(a.x) | (e2m1(a.y) << 4);
    unsigned b1 = e2m1(a.z) | (e2m1(a.w) << 4);
    unsigned b2 = e2m1(b.x) | (e2m1(b.y) << 4);
    unsigned b3 = e2m1(b.z) | (e2m1(b.w) << 4);
    return b0 | (b1 << 8) | (b2 << 16) | (b3 << 24);
}

// ---------------------------------------------------------------------------
// fp32 -> fp4 TRANSPOSED X: plane p (0..31) of [NTOK][16B]; plane p row r
// holds elems [p*32, p*32+32) of token r. Block = 8 rows x 32 planes.
// (Validated layout from rounds 9-11.)
// ---------------------------------------------------------------------------
__global__ __launch_bounds__(256) void convX4T(const float* __restrict__ X,
                                               unsigned char* __restrict__ Xq) {
    int r8 = threadIdx.x >> 5;            // 0..7
    int p  = threadIdx.x & 31;            // plane 0..31
    int row = blockIdx.x * 8 + r8;
    const float4* src = (const float4*)(X + (size_t)row * DD + p * 32);
    uint4 o;
    o.x = pack8_e2m1(src[0], src[1]);
    o.y = pack8_e2m1(src[2], src[3]);
    o.z = pack8_e2m1(src[4], src[5]);
    o.w = pack8_e2m1(src[6], src[7]);
    *(uint4*)(Xq + ((size_t)p * NTOK + row) * 16) = o;
}

// fp32 -> fp4 TRANSPOSED (32*E), zero-padded to VPAD2 rows.
__global__ __launch_bounds__(256) void convE4T(const float* __restrict__ E,
                                               unsigned char* __restrict__ Eq) {
    int r8 = threadIdx.x >> 5;
    int p  = threadIdx.x & 31;
    int row = blockIdx.x * 8 + r8;
    float4 f[8];
    #pragma unroll
    for (int j = 0; j < 8; ++j) f[j] = make_float4(0.f, 0.f, 0.f, 0.f);
    if (row < VV) {
        const float4* src = (const float4*)(E + (size_t)row * DD + p * 32);
        #pragma unroll
        for (int j = 0; j < 8; ++j) {
            float4 v = src[j];
            v.x *= 32.f; v.y *= 32.f; v.z *= 32.f; v.w *= 32.f;
            f[j] = v;
        }
    }
    uint4 o;
    o.x = pack8_e2m1(f[0], f[1]);
    o.y = pack8_e2m1(f[2], f[3]);
    o.z = pack8_e2m1(f[4], f[5]);
    o.w = pack8_e2m1(f[6], f[7]);
    *(uint4*)(Eq + ((size_t)p * VPAD2 + row) * 16) = o;
}

// ---------------------------------------------------------------------------
// Label logits in fp32 (exact). One block per token.
// ---------------------------------------------------------------------------
__global__ __launch_bounds__(256) void ce_label(
    const float* __restrict__ X, const float* __restrict__ E,
    const float* __restrict__ bias, const int* __restrict__ labels,
    float* __restrict__ lab_out)
{
    int t = blockIdx.x;
    int lbl = labels[t];
    const float4* x = (const float4*)(X + (size_t)t * DD);
    const float4* e = (const float4*)(E + (size_t)lbl * DD);
    int i = threadIdx.x;
    float4 a = x[i], b4 = e[i];
    float s = a.x*b4.x + a.y*b4.y + a.z*b4.z + a.w*b4.w;
    #pragma unroll
    for (int off = 32; off; off >>= 1) s += __shfl_down(s, off, 64);
    __shared__ float red[4];
    if ((threadIdx.x & 63) == 0) red[threadIdx.x >> 6] = s;
    __syncthreads();
    if (threadIdx.x == 0)
        lab_out[t] = red[0] + red[1] + red[2] + red[3] + bias[lbl];
}

// ---------------------------------------------------------------------------
// Fused MX-fp4 MFMA GEMM, 128x128 tile, direct-to-register operands and
// INLINE-ASM MFMA with 4-register fp4 operand form. 256 threads = 4 waves
// (2M x 2N); wave tile 64x64 = 2x2 grid of 32x32x64 MFMAs, acc[2][2] f32x16.
//
// The gfx950 assembler sizes f8f6f4 source operands by cbsz/blgp: with
// cbsz:4 blgp:4 (fp4 e2m1) A and B are 4-VGPR tuples -- exactly one
// global_load_dwordx4 result each, so there is ZERO operand marshalling
// (the round-11 builtin forced i32x8 and cost ~1000 v_movs/wave).
// Non-scaled mnemonic = implicit scale 1.0 == the validated 0x7F scales.
// Element mapping identical to rounds 9-11 (validated, absmax 0).
// Hazards (asm is opaque to the compiler): 3x s_nop 7 after the K-loop
// covers MFMA->VALU RAW on acc; load->MFMA deps get compiler s_waitcnt.
// ---------------------------------------------------------------------------
struct FragSet { i32x4 a[2][2]; i32x4 b[2][2]; };   // [idx][kk]

__global__ __launch_bounds__(256, 3) void ce_a4(
    const unsigned char* __restrict__ Xq, const unsigned char* __restrict__ Eq,
    const float* __restrict__ bias, float* __restrict__ pairs)
{
    __shared__ float sums[256];      // epilogue only (1 KB)

    const int tid  = threadIdx.x;
    const int lane = tid & 63;
    const int w    = tid >> 6;       // 0..3
    const int wr   = w >> 1;         // 0..1  M half (64 rows)
    const int wc   = w & 1;          // 0..1  N half (64 cols)
    const int h    = lane >> 5;      // k-half within a 64-elem MFMA group
    const int r32  = lane & 31;      // row (A) / col (B) within 32

    // bijective XCD chunking; nc-major within each XCD (E-panel L2 locality)
    const int l       = blockIdx.x;
    const int logical = (l & 7) * CPX2 + (l >> 3);
    const int nc   = logical >> 5;   // / NMT2(32)
    const int mt   = logical & 31;
    const int tok0 = mt * BM2;
    const int v0   = nc * BN2;

    // per-lane fragment bases (plane h; plane index advances by 4t + 2kk)
    const unsigned char* pA = Xq + ((size_t)h * NTOK  + tok0 + wr * 64 + r32) * 16;
    const unsigned char* pB = Eq + ((size_t)h * VPAD2 + v0   + wc * 64 + r32) * 16;

#define LOADSET(F, t) do {                                                    \
        const size_t _o0 = (size_t)(4 * (t)) * PSA;                           \
        const size_t _o1 = _o0 + 2 * PSA;                                     \
        const size_t _p0 = (size_t)(4 * (t)) * PSB;                           \
        const size_t _p1 = _p0 + 2 * PSB;                                     \
        F.a[0][0] = *(const i32x4*)(pA + _o0);                                \
        F.a[1][0] = *(const i32x4*)(pA + _o0 + 512);                          \
        F.a[0][1] = *(const i32x4*)(pA + _o1);                                \
        F.a[1][1] = *(const i32x4*)(pA + _o1 + 512);                          \
        F.b[0][0] = *(const i32x4*)(pB + _p0);                                \
        F.b[1][0] = *(const i32x4*)(pB + _p0 + 512);                          \
        F.b[0][1] = *(const i32x4*)(pB + _p1);                                \
        F.b[1][1] = *(const i32x4*)(pB + _p1 + 512);                          \
    } while (0)

// one 32x32x64 fp4 MFMA, 4-reg A/B operands, implicit scale = 1.0
#define MFMA1(ACC, A4, B4)                                                    \
    asm("v_mfma_f32_32x32x64_f8f6f4 %0, %1, %2, %0 cbsz:4 blgp:4"             \
        : "+v"(ACC) : "v"(A4), "v"(B4))

#define MFMASET(F) do {                                                       \
        __builtin_amdgcn_s_setprio(1);                                        \
        MFMA1(acc[0][0], F.a[0][0], F.b[0][0]);                               \
        MFMA1(acc[0][1], F.a[0][0], F.b[1][0]);                               \
        MFMA1(acc[1][0], F.a[1][0], F.b[0][0]);                               \
        MFMA1(acc[1][1], F.a[1][0], F.b[1][0]);                               \
        MFMA1(acc[0][0], F.a[0][1], F.b[0][1]);                               \
        MFMA1(acc[0][1], F.a[0][1], F.b[1][1]);                               \
        MFMA1(acc[1][0], F.a[1][1], F.b[0][1]);                               \
        MFMA1(acc[1][1], F.a[1][1], F.b[1][1]);                               \
        __builtin_amdgcn_s_setprio(0);                                        \
    } while (0)

    f32x16 acc[2][2];
    #pragma unroll
    for (int mi = 0; mi < 2; ++mi)
        #pragma unroll
        for (int ni = 0; ni < 2; ++ni)
            #pragma unroll
            for (int g = 0; g < 16; ++g)
                acc[mi][ni][g] = 0.f;

    FragSet F, G;
    LOADSET(F, 0);
    #pragma unroll 1
    for (int t = 0; t < NKT2; t += 2) {
        LOADSET(G, t + 1);           // prefetch t+1 while computing t
        MFMASET(F);
        if (t + 2 < NKT2) LOADSET(F, t + 2);
        MFMASET(G);
    }
#undef LOADSET
#undef MFMASET
#undef MFMA1

    // MFMA -> VALU RAW hazard guard (asm MFMAs are opaque to the compiler)
    asm volatile("s_nop 7\n\ts_nop 7\n\ts_nop 7" ::: "memory");

    // ---- epilogue: fixed-max sum of exp (base-2), masked pad cols ----
    // acc = X . (32 E); 1/32 folded into the exp2 slope (L2E32).
    // 32x32 C/D map: col = lane&31, row = (g&3) + 8*(g>>2) + 4*h
    float bb[2];
    #pragma unroll
    for (int ni = 0; ni < 2; ++ni) {
        int v = v0 + wc * 64 + ni * 32 + r32;
        bb[ni] = (v < VV) ? bias[v] * LOG2E : -INFINITY;
    }

    #pragma unroll
    for (int mi = 0; mi < 2; ++mi) {
        float run[16];
        #pragma unroll
        for (int g = 0; g < 16; ++g)
            run[g] = exp2f(fmaf(acc[mi][0][g], L2E32, bb[0]))
                   + exp2f(fmaf(acc[mi][1][g], L2E32, bb[1]));
        #pragma unroll
        for (int g = 0; g < 16; ++g) {
            float s = run[g];
            s += __shfl_xor(s, 1);  s += __shfl_xor(s, 2);
            s += __shfl_xor(s, 4);  s += __shfl_xor(s, 8);
            s += __shfl_xor(s, 16);
            run[g] = s;
        }
        if (r32 == 0) {
            #pragma unroll
            for (int g = 0; g < 16; ++g) {
                int rl = (g & 3) + 8 * (g >> 2) + 4 * h;
                sums[wc * 128 + wr * 64 + mi * 32 + rl] = run[g];
            }
        }
    }
    __syncthreads();
    if (tid < 128) {
        float S = sums[tid] + sums[128 + tid];
        pairs[(size_t)nc * NTOK + tok0 + tid] = S;
    }
}

// ---------------------------------------------------------------------------
// Combine NC2 partial sums per token -> per-block loss partial sums
// ---------------------------------------------------------------------------
__global__ __launch_bounds__(256) void ce_combine(
    const float* __restrict__ pairs, const float* __restrict__ lab,
    float* __restrict__ partials)
{
    int t = blockIdx.x * 256 + threadIdx.x;    // grid 16 x 256 = 4096 tokens
    float S = 0.f;
    for (int c = 0; c < NC2; ++c) S += pairs[(size_t)c * NTOK + t];
    float acc = log2f(S) * LN2F - lab[t];
    #pragma unroll
    for (int off = 32; off; off >>= 1) acc += __shfl_down(acc, off, 64);
    __shared__ float red[4];
    if ((threadIdx.x & 63) == 0) red[threadIdx.x >> 6] = acc;
    __syncthreads();
    if (threadIdx.x == 0)
        partials[blockIdx.x] = red[0] + red[1] + red[2] + red[3];
}

__global__ void ce_sum(const float* __restrict__ partials, float* __restrict__ out) {
    if (threadIdx.x == 0) {
        float s = 0.f;
        for (int i = 0; i < 16; ++i) s += partials[i];
        out[0] = s / (float)NTOK;
    }
}

// ---------------------------------------------------------------------------
// FALLBACK path (round-1 fp32 kernels) — used only if ws_size is too small
// ---------------------------------------------------------------------------
__global__ __launch_bounds__(256) void ce_partial_old(
    const float* __restrict__ X, const float* __restrict__ E,
    const float* __restrict__ bias, float* __restrict__ pairs)
{
    int ttile = blockIdx.x;
    int chunk = blockIdx.y;
    int tid = threadIdx.x;
    int ty = tid >> 4;
    int tx = tid & 15;

    __shared__ float As_[TT][KT + 1];
    __shared__ float Bs_[VT][KT + 1];

    int tok0 = ttile * TT;
    float run_m = -INFINITY, run_s = 0.f;

    for (int sub = 0; sub < NSUB_O; ++sub) {
        int v0 = chunk * CHUNK_O + sub * VT;
        float acc[8];
        #pragma unroll
        for (int c = 0; c < 8; ++c) acc[c] = 0.f;

        for (int k0 = 0; k0 < DD; k0 += KT) {
            __syncthreads();
            {
                const float2 a2 = *(const float2*)(X + (size_t)(tok0 + ty) * DD + k0 + 2 * tx);
                As_[ty][2 * tx]     = a2.x;
                As_[ty][2 * tx + 1] = a2.y;
            }
            #pragma unroll
            for (int j = 0; j < 4; ++j) {
                int idx = tid + 256 * j;
                int r  = idx >> 3;
                int c4 = (idx & 7) << 2;
                int v = v0 + r;
                float4 b4 = make_float4(0.f, 0.f, 0.f, 0.f);
                if (v < VV)
                    b4 = *(const float4*)(E + (size_t)v * DD + k0 + c4);
                Bs_[r][c4]     = b4.x;
                Bs_[r][c4 + 1] = b4.y;
                Bs_[r][c4 + 2] = b4.z;
                Bs_[r][c4 + 3] = b4.w;
            }
            __syncthreads();
            #pragma unroll
            for (int k = 0; k < KT; ++k) {
                float a = As_[ty][k];
                #pragma unroll
                for (int c = 0; c < 8; ++c)
                    acc[c] += a * Bs_[tx + 16 * c][k];
            }
        }

        float lv[8];
        float lm = -INFINITY;
        #pragma unroll
        for (int c = 0; c < 8; ++c) {
            int v = v0 + tx + 16 * c;
            float lg = (v < VV) ? acc[c] + bias[v] : -INFINITY;
            lv[c] = lg;
            lm = fmaxf(lm, lg);
        }
        if (lm != -INFINITY) {
            float nm = fmaxf(run_m, lm);
            float s = run_s * expf(run_m - nm);
            #pragma unroll
            for (int c = 0; c < 8; ++c) s += expf(lv[c] - nm);
            run_m = nm; run_s = s;
        }
    }

    #pragma unroll
    for (int off = 1; off < 16; off <<= 1) {
        float om = __shfl_xor(run_m, off, 64);
        float os = __shfl_xor(run_s, off, 64);
        if (os > 0.f) {
            if (om > run_m) { run_s = run_s * expf(run_m - om) + os; run_m = om; }
            else            { run_s += os * expf(om - run_m); }
        }
    }
    if (tx == 0) {
        size_t o = ((size_t)chunk * NTOK + tok0 + ty) * 2;
        pairs[o]     = run_m;
        pairs[o + 1] = run_s;
    }
}

__global__ __launch_bounds__(256) void ce_final_old(
    const float* __restrict__ pairs, const float* __restrict__ lab,
    float* __restrict__ out)
{
    int tid = threadIdx.x;
    float acc = 0.f;
    for (int t = tid; t < NTOK; t += 256) {
        float M = -INFINITY, S = 0.f;
        for (int c = 0; c < NCHUNK_O; ++c) {
            size_t o = ((size_t)c * NTOK + t) * 2;
            float m = pairs[o], s = pairs[o + 1];
            if (s > 0.f) {
                if (m > M) { S = S * expf(M - m) + s; M = m; }
                else       { S += s * expf(m - M); }
            }
        }
        acc += (M + logf(S)) - lab[t];
    }
    #pragma unroll
    for (int off = 32; off; off >>= 1) acc += __shfl_down(acc, off, 64);
    __shared__ float red[4];
    if ((tid & 63) == 0) red[tid >> 6] = acc;
    __syncthreads();
    if (tid == 0)
        out[0] = (red[0] + red[1] + red[2] + red[3]) / (float)NTOK;
}

// ---------------------------------------------------------------------------
extern "C" void kernel_launch(void* const* d_in, const int* in_sizes, int n_in,
                              void* d_out, int out_size, void* d_ws, size_t ws_size,
                              hipStream_t stream) {
    const float* X      = (const float*)d_in[0];   // [4096,1024]
    const float* E      = (const float*)d_in[1];   // [50257,1024]
    const float* bias   = (const float*)d_in[2];   // [50257]
    const int*   labels = (const int*)d_in[3];     // [4096]
    float* out = (float*)d_out;

    char* ws = (char*)d_ws;
    const size_t off_lab   = 0;                                  // 16 KB
    const size_t off_pairs = 16384;
    const size_t sz_pairs  = (size_t)NC2 * NTOK * 4;             // ~6.4 MB
    const size_t off_part  = off_pairs + sz_pairs;
    const size_t off_Xq    = off_part + 1024;                    // 16B aligned
    const size_t off_Eq    = off_Xq + (size_t)NTOK * RB;         // 2 MB
    const size_t need      = off_Eq + (size_t)VPAD2 * RB;        // ~34 MB

    float* lab = (float*)(ws + off_lab);

    if (ws_size >= need) {
        unsigned char* Xq = (unsigned char*)(ws + off_Xq);
        unsigned char* Eq = (unsigned char*)(ws + off_Eq);
        float* pairs    = (float*)(ws + off_pairs);
        float* partials = (float*)(ws + off_part);

        convX4T<<<NTOK / 8, 256, 0, stream>>>(X, Xq);
        convE4T<<<VPAD2 / 8, 256, 0, stream>>>(E, Eq);
        ce_label<<<NTOK, 256, 0, stream>>>(X, E, bias, labels, lab);
        ce_a4<<<NBLK2, 256, 0, stream>>>(Xq, Eq, bias, pairs);
        ce_combine<<<16, 256, 0, stream>>>(pairs, lab, partials);
        ce_sum<<<1, 64, 0, stream>>>(partials, out);
    } else {
        float* pairs = (float*)(ws + 16384);
        ce_label<<<NTOK, 256, 0, stream>>>(X, E, bias, labels, lab);
        dim3 grid(NTTILE_O, NCHUNK_O);
        ce_partial_old<<<grid, 256, 0, stream>>>(X, E, bias, pairs);
        ce_final_old<<<1, 256, 0, stream>>>(pairs, lab, out);
    }
}